// Round 1
// baseline (160.127 us; speedup 1.0000x reference)
//
#include <hip/hip_runtime.h>
#include <math.h>

#define D_MODEL 300
#define LSEQ    512
#define NBATCH  300
#define SPLIT   16
#define LCH     (LSEQ / SPLIT)      // 32 l-values per block
#define NG      4                   // parallel l-streams (groups) per block
#define LPG     (LCH / NG)          // 8 l-values per stream
#define NR      75                  // float4 lanes per row (75*4 = 300)
#define KCH     (D_MODEL / 4)       // 75, fc1 k-chunk
#define JPB     2                   // j-rows per fc1 block
#define SCALE   17.32050807568877f  // sqrt(300)

// pe[l, e]: e even -> sin(l * div[e/2]); e odd -> cos(l * div[e/2])
__global__ void pe_kernel(float* __restrict__ pe) {
    int idx = blockIdx.x * blockDim.x + threadIdx.x;
    if (idx >= LSEQ * D_MODEL) return;
    int l = idx / D_MODEL;
    int e = idx - l * D_MODEL;
    int k = e >> 1;
    float dv = expf((float)(2 * k) * (-9.210340371976184f / 300.0f));
    float arg = (float)l * dv;
    pe[idx] = (e & 1) ? cosf(arg) : sinf(arg);
}

// Dm[i][e] += sum_{l in chunk} s[l] * (SCALE*emb1[x1[i,l]][e] + pe[l][e])
// v2: 8 l's per stream, loads issued in explicit batches of 4 gather + 4 pe
// float4s into named registers (compile-time indices) so the compiler keeps
// >=8 global loads in flight per wave instead of serializing on 28 VGPRs.
__global__ void diag_fused_kernel(const int* __restrict__ x1, const int* __restrict__ x2,
                                  const float* __restrict__ emb1, const float* __restrict__ emb2,
                                  const float* __restrict__ pe, float* __restrict__ Dm) {
    __shared__ int    x1ch[LCH];
    __shared__ float  sch[LCH];
    __shared__ float4 part[NG][NR];
    const int i   = blockIdx.x;   // batch index (== diagonal index)
    const int sp  = blockIdx.y;   // l-chunk
    const int tid = threadIdx.x;
    const int l0  = sp * LCH;

    if (tid < LCH) {
        const int l = l0 + tid;
        x1ch[tid] = x1[i * LSEQ + l];
        int idx2  = x2[i * LSEQ + l];
        sch[tid]  = emb2[(size_t)idx2 * D_MODEL + i] * SCALE + pe[l * D_MODEL + i];
    }
    __syncthreads();

    const int g = tid / NR;       // l-stream
    const int r = tid - g * NR;   // float4 index within row

    if (tid < NG * NR) {
        const int lb = g * LPG;   // this stream owns l0+lb .. l0+lb+LPG-1
        float ax = 0.f, ay = 0.f, az = 0.f, aw = 0.f;
        #pragma unroll
        for (int qq = 0; qq < LPG; qq += 4) {
            // ---- issue 8 independent loads (4 gathers + 4 pe) ----
            const float4 ev0 = ((const float4*)(emb1 + (size_t)x1ch[lb + qq + 0] * D_MODEL))[r];
            const float4 ev1 = ((const float4*)(emb1 + (size_t)x1ch[lb + qq + 1] * D_MODEL))[r];
            const float4 ev2 = ((const float4*)(emb1 + (size_t)x1ch[lb + qq + 2] * D_MODEL))[r];
            const float4 ev3 = ((const float4*)(emb1 + (size_t)x1ch[lb + qq + 3] * D_MODEL))[r];
            const float4 pv0 = ((const float4*)(pe + (size_t)(l0 + lb + qq + 0) * D_MODEL))[r];
            const float4 pv1 = ((const float4*)(pe + (size_t)(l0 + lb + qq + 1) * D_MODEL))[r];
            const float4 pv2 = ((const float4*)(pe + (size_t)(l0 + lb + qq + 2) * D_MODEL))[r];
            const float4 pv3 = ((const float4*)(pe + (size_t)(l0 + lb + qq + 3) * D_MODEL))[r];
            const float s0 = sch[lb + qq + 0];
            const float s1 = sch[lb + qq + 1];
            const float s2 = sch[lb + qq + 2];
            const float s3 = sch[lb + qq + 3];
            // ---- consume ----
            ax = fmaf(s0, fmaf(ev0.x, SCALE, pv0.x), ax);
            ay = fmaf(s0, fmaf(ev0.y, SCALE, pv0.y), ay);
            az = fmaf(s0, fmaf(ev0.z, SCALE, pv0.z), az);
            aw = fmaf(s0, fmaf(ev0.w, SCALE, pv0.w), aw);
            ax = fmaf(s1, fmaf(ev1.x, SCALE, pv1.x), ax);
            ay = fmaf(s1, fmaf(ev1.y, SCALE, pv1.y), ay);
            az = fmaf(s1, fmaf(ev1.z, SCALE, pv1.z), az);
            aw = fmaf(s1, fmaf(ev1.w, SCALE, pv1.w), aw);
            ax = fmaf(s2, fmaf(ev2.x, SCALE, pv2.x), ax);
            ay = fmaf(s2, fmaf(ev2.y, SCALE, pv2.y), ay);
            az = fmaf(s2, fmaf(ev2.z, SCALE, pv2.z), az);
            aw = fmaf(s2, fmaf(ev2.w, SCALE, pv2.w), aw);
            ax = fmaf(s3, fmaf(ev3.x, SCALE, pv3.x), ax);
            ay = fmaf(s3, fmaf(ev3.y, SCALE, pv3.y), ay);
            az = fmaf(s3, fmaf(ev3.z, SCALE, pv3.z), az);
            aw = fmaf(s3, fmaf(ev3.w, SCALE, pv3.w), aw);
        }
        part[g][r] = make_float4(ax, ay, az, aw);
    }
    __syncthreads();

    if (g == 0 && tid < NR) {
        float4 p0 = part[0][r], p1 = part[1][r], p2 = part[2][r], p3 = part[3][r];
        float* dst = Dm + i * D_MODEL + 4 * r;
        atomicAdd(dst + 0, p0.x + p1.x + p2.x + p3.x);
        atomicAdd(dst + 1, p0.y + p1.y + p2.y + p3.y);
        atomicAdd(dst + 2, p0.z + p1.z + p2.z + p3.z);
        atomicAdd(dst + 3, p0.w + p1.w + p2.w + p3.w);
    }
}

// fc1 k-split partial, JPB j-rows per block for Dm reuse:
// Hpre[j][e] += sum_{k in chunk} w1[j,k] * Dm[k][e]
__global__ void fc1_kernel(const float* __restrict__ w1, const float* __restrict__ Dm,
                           float* __restrict__ Hpre) {
    const int j0  = blockIdx.x * JPB;
    const int sp  = blockIdx.y;
    const int tid = threadIdx.x;
    const int k0  = sp * KCH;
    if (tid >= D_MODEL) return;
    const float* w1r0 = w1 + (j0 + 0) * D_MODEL + k0;
    const float* w1r1 = w1 + (j0 + 1) * D_MODEL + k0;
    float acc0 = 0.0f, acc1 = 0.0f;
    #pragma unroll 5
    for (int k = 0; k < KCH; ++k) {
        float d = Dm[(k0 + k) * D_MODEL + tid];
        acc0 = fmaf(w1r0[k], d, acc0);
        acc1 = fmaf(w1r1[k], d, acc1);
    }
    atomicAdd(&Hpre[(j0 + 0) * D_MODEL + tid], acc0);
    atomicAdd(&Hpre[(j0 + 1) * D_MODEL + tid], acc1);
}

// Fused bias + relu + fc2 + softmax. Block = 256 thr = 64 e-lanes x 4 j-chunks.
__global__ void fc2_softmax_kernel(const float* __restrict__ Hpre, const float* __restrict__ b1,
                                   const float* __restrict__ w2, const float* __restrict__ b2,
                                   float* __restrict__ out) {
    __shared__ float sm[4][4][64];   // [jc][o][e_loc]
    const int tid   = threadIdx.x;
    const int e_loc = tid & 63;
    const int jc    = tid >> 6;
    const int e     = blockIdx.x * 64 + e_loc;

    float a0 = 0.f, a1 = 0.f, a2 = 0.f, a3 = 0.f;
    if (e < D_MODEL) {
        const int j0 = jc * 75;
        #pragma unroll 5
        for (int j = j0; j < j0 + 75; ++j) {
            float h = fmaxf(Hpre[j * D_MODEL + e] + b1[j], 0.0f);
            a0 = fmaf(h, w2[0 * D_MODEL + j], a0);
            a1 = fmaf(h, w2[1 * D_MODEL + j], a1);
            a2 = fmaf(h, w2[2 * D_MODEL + j], a2);
            a3 = fmaf(h, w2[3 * D_MODEL + j], a3);
        }
    }
    sm[jc][0][e_loc] = a0; sm[jc][1][e_loc] = a1;
    sm[jc][2][e_loc] = a2; sm[jc][3][e_loc] = a3;
    __syncthreads();

    if (jc == 0 && e < D_MODEL) {
        float l0 = b2[0] + sm[0][0][e_loc] + sm[1][0][e_loc] + sm[2][0][e_loc] + sm[3][0][e_loc];
        float l1 = b2[1] + sm[0][1][e_loc] + sm[1][1][e_loc] + sm[2][1][e_loc] + sm[3][1][e_loc];
        float l2 = b2[2] + sm[0][2][e_loc] + sm[1][2][e_loc] + sm[2][2][e_loc] + sm[3][2][e_loc];
        float l3 = b2[3] + sm[0][3][e_loc] + sm[1][3][e_loc] + sm[2][3][e_loc] + sm[3][3][e_loc];
        float m  = fmaxf(fmaxf(l0, l1), fmaxf(l2, l3));
        float x0 = expf(l0 - m), x1 = expf(l1 - m), x2 = expf(l2 - m), x3 = expf(l3 - m);
        float inv = 1.0f / (x0 + x1 + x2 + x3);
        out[e * 4 + 0] = x0 * inv;
        out[e * 4 + 1] = x1 * inv;
        out[e * 4 + 2] = x2 * inv;
        out[e * 4 + 3] = x3 * inv;
    }
}

extern "C" void kernel_launch(void* const* d_in, const int* in_sizes, int n_in,
                              void* d_out, int out_size, void* d_ws, size_t ws_size,
                              hipStream_t stream) {
    const int*   x1   = (const int*)d_in[0];
    const int*   x2   = (const int*)d_in[1];
    const float* emb1 = (const float*)d_in[2];
    const float* emb2 = (const float*)d_in[3];
    const float* w1   = (const float*)d_in[4];
    const float* b1   = (const float*)d_in[5];
    const float* w2   = (const float*)d_in[6];
    const float* b2   = (const float*)d_in[7];
    float* out = (float*)d_out;

    char* ws = (char*)d_ws;
    float* pe   = (float*)ws;                 // 512*300*4 = 614400 B
    float* Dm   = (float*)(ws + 614400);      // 300*300*4 = 360000 B
    float* Hpre = (float*)(ws + 974400);      // 300*300*4 = 360000 B

    // zero the two atomic-accumulated buffers (contiguous)
    (void)hipMemsetAsync(Dm, 0, 2 * 360000, stream);

    pe_kernel<<<(LSEQ * D_MODEL + 255) / 256, 256, 0, stream>>>(pe);
    diag_fused_kernel<<<dim3(NBATCH, SPLIT), 320, 0, stream>>>(x1, x2, emb1, emb2, pe, Dm);
    fc1_kernel<<<dim3(D_MODEL / JPB, 4), 320, 0, stream>>>(w1, Dm, Hpre);
    fc2_softmax_kernel<<<(D_MODEL + 63) / 64, 256, 0, stream>>>(Hpre, b1, w2, b2, out);
}